// Round 9
// baseline (39.822 us; speedup 1.0000x reference)
//
#include <hip/hip_runtime.h>

#define FLOWS 16
#define NE 512                        // intervals per flow
#define TAB_QWORDS (FLOWS * NE)       // 8192 x 8B = 64 KB
#define TAB_BYTES  (TAB_QWORDS * 8)

#define BLOCK 1024
#define TROWS 4

// ---------------- MLP evaluator (table builder only) ----------------
__device__ __forceinline__ float tanh_fast(float x) {
    float e = __expf(2.0f * x);
    return 1.0f - 2.0f * __builtin_amdgcn_rcpf(e + 1.0f);
}

__device__ __forceinline__ float2 eval_mlp(int l, float z0,
        const float* __restrict__ W1, const float* __restrict__ B1,
        const float* __restrict__ W2, const float* __restrict__ B2,
        const float* __restrict__ W3, const float* __restrict__ B3,
        const float* __restrict__ W4, const float* __restrict__ B4) {
    const float* w1 = W1 + l * 10;
    const float* c1 = B1 + l * 10;
    const float* w2 = W2 + l * 100;
    const float* c2 = B2 + l * 10;
    const float* w3 = W3 + l * 200;
    const float* c3 = B3 + l * 20;
    const float* w4 = W4 + l * 40;
    const float* c4 = B4 + l * 2;

    float h1[10];
#pragma unroll
    for (int j = 0; j < 10; ++j)
        h1[j] = fmaxf(fmaf(z0, w1[j], c1[j]), 0.0f);

    float h2[10];
#pragma unroll
    for (int j = 0; j < 10; ++j) {
        float acc = c2[j];
#pragma unroll
        for (int i = 0; i < 10; ++i) acc = fmaf(h1[i], w2[i * 10 + j], acc);
        h2[j] = fmaxf(acc, 0.0f);
    }

    float h3[20];
#pragma unroll
    for (int j = 0; j < 20; ++j) {
        float acc = c3[j];
#pragma unroll
        for (int i = 0; i < 10; ++i) acc = fmaf(h2[i], w3[i * 20 + j], acc);
        h3[j] = tanh_fast(acc);
    }

    float ls = c4[0], sh = c4[1];
#pragma unroll
    for (int i = 0; i < 20; ++i) {
        ls = fmaf(h3[i], w4[i * 2 + 0], ls);
        sh = fmaf(h3[i], w4[i * 2 + 1], sh);
    }
    return make_float2(ls * 1.4426950408889634f, sh);  // (log_scale*log2e, shift)
}

// Warp: u = sign(z0)*log2(1+8|z0|), clamped to [-10,10]; nodes u_i = -10 + i*(20/512)
// 20/512 = 0.0390625 exact. Covers |z0| <= 127.875; MLP output is asymptotically
// constant in z0 (tanh saturates), so clamping beyond range is benign.
__device__ __forceinline__ float node_z0(int i) {
    float u = fmaf((float)i, 0.0390625f, -10.0f);
    float m = 0.125f * (exp2f(fabsf(u)) - 1.0f);
    return u < 0.0f ? -m : m;
}

// int16 fixed-point, scale 2^-11 (range +-16, resolution 4.88e-4)
__device__ __forceinline__ int enc_i16(float v) {
    int q = (int)rintf(v * 2048.0f);
    q = q > 32767 ? 32767 : q;
    q = q < -32768 ? -32768 : q;
    return q;
}

// entry i (uint2): .x = {i16 ls2_i | i16 sh_i<<16}, .y = same for (node_{i+1} - node_i)
// deltas are exact int differences of the encoded nodes -> fr=1 reproduces node i+1.
__global__ __launch_bounds__(256) void build_table_i16(
        const float* __restrict__ W1, const float* __restrict__ B1,
        const float* __restrict__ W2, const float* __restrict__ B2,
        const float* __restrict__ W3, const float* __restrict__ B3,
        const float* __restrict__ W4, const float* __restrict__ B4,
        uint2* __restrict__ gtab) {
    int t = blockIdx.x * blockDim.x + threadIdx.x;
    if (t >= TAB_QWORDS) return;
    int l = t >> 9, i = t & (NE - 1);
    float2 r0 = eval_mlp(l, node_z0(i),     W1, B1, W2, B2, W3, B3, W4, B4);
    float2 r1 = eval_mlp(l, node_z0(i + 1), W1, B1, W2, B2, W3, B3, W4, B4);
    int ls0 = enc_i16(r0.x), sh0 = enc_i16(r0.y);
    int ls1 = enc_i16(r1.x), sh1 = enc_i16(r1.y);
    uint2 e;
    e.x = (unsigned)(ls0 & 0xFFFF) | ((unsigned)(sh0 & 0xFFFF) << 16);
    e.y = (unsigned)((ls1 - ls0) & 0xFFFF) | ((unsigned)((sh1 - sh0) & 0xFFFF) << 16);
    gtab[t] = e;
}

// ---------------- main kernel: 64 KB LDS table, 2 blocks/CU ----------------
__global__ __launch_bounds__(BLOCK, 8) void realnvp_i16(
        const float* __restrict__ x,
        const uint2* __restrict__ gtab,
        float* __restrict__ out, int nrows) {
    __shared__ uint2 st[TAB_QWORDS];  // 64 KB

    {   // stage table, 16 B/lane coalesced (4 iters)
        uint4* d = (uint4*)st;
        const uint4* s = (const uint4*)gtab;
#pragma unroll
        for (int k = 0; k < TAB_QWORDS / 2; k += BLOCK)
            d[k + threadIdx.x] = s[k + threadIdx.x];
    }
    __syncthreads();

    const int rbase = blockIdx.x * (TROWS * BLOCK) + threadIdx.x;

    float z0[TROWS], z1[TROWS], ldS[TROWS];
#pragma unroll
    for (int r = 0; r < TROWS; ++r) {
        const int row = rbase + r * BLOCK;
        float2 xv = (row < nrows) ? reinterpret_cast<const float2*>(x)[row]
                                  : make_float2(0.0f, 0.0f);
        z0[r] = xv.x; z1[r] = xv.y; ldS[r] = 0.0f;
    }

    const float INV_DU = 25.6f;          // 512/20
    const float SCALE  = 4.8828125e-4f;  // 2^-11

    // one coupling step: index zi[], multiply zm[], write zo[]
    auto step = [&](const uint2* tf, const float* zi, const float* zm, float* zo) {
        int idx[TROWS]; float fr[TROWS];
#pragma unroll
        for (int r = 0; r < TROWS; ++r) {
            float a  = fmaf(fabsf(zi[r]), 8.0f, 1.0f);   // 1 + |z|/0.125
            float lg = __log2f(a);
            float u  = copysignf(lg, zi[r]);
            float fi = fmaf(u, INV_DU, 256.0f);
            fi = fminf(fmaxf(fi, 0.0f), 511.99f);
            float tt = truncf(fi);
            idx[r] = (int)tt;
            fr[r]  = fi - tt;
        }
        uint2 e[TROWS];
#pragma unroll
        for (int r = 0; r < TROWS; ++r)
            e[r] = tf[idx[r]];                           // one ds_read_b64 each
#pragma unroll
        for (int r = 0; r < TROWS; ++r) {
            float b0 = (float)(short)(e[r].x);
            float b1 = (float)(short)(e[r].x >> 16);
            float d0 = (float)(short)(e[r].y);
            float d1 = (float)(short)(e[r].y >> 16);
            float lsS = fmaf(fr[r], d0, b0);             // scaled by 2^11
            float shS = fmaf(fr[r], d1, b1);
            float e2  = exp2f(lsS * SCALE);
            zo[r] = fmaf(e2, zm[r], shS * SCALE);
            ldS[r] += lsS;
        }
    };

    float w[TROWS], v[TROWS];
#pragma unroll 1
    for (int lp = 0; lp < FLOWS; lp += 2) {
        step(st + (lp << 9),       z0, z1, w);   // pair -> (w, z0)
        step(st + ((lp + 1) << 9), w,  z0, v);   // pair -> (v, w)
#pragma unroll
        for (int r = 0; r < TROWS; ++r) { z0[r] = v[r]; z1[r] = w[r]; }
    }

    float* out_lp = out;
    float2* out_z = reinterpret_cast<float2*>(out + nrows);
    const float LDC = (float)(0.6931471805599453 / 2048.0);  // ln2 * 2^-11
#pragma unroll
    for (int r = 0; r < TROWS; ++r) {
        const int row = rbase + r * BLOCK;
        if (row < nrows) {
            const float z0n = z1[r], z1n = z0[r];
            const float ld  = ldS[r] * LDC;
            const float lp  = fmaf(-0.5f, fmaf(z0n, z0n, z1n * z1n), -1.8378770664093453f) + ld;
            out_lp[row] = lp;
            out_z[row]  = make_float2(z0n, z1n);
        }
    }
}

// ---------------- launcher ----------------
extern "C" void kernel_launch(void* const* d_in, const int* in_sizes, int n_in,
                              void* d_out, int out_size, void* d_ws, size_t ws_size,
                              hipStream_t stream) {
    const float* x  = (const float*)d_in[0];
    const float* W1 = (const float*)d_in[1];
    const float* B1 = (const float*)d_in[2];
    const float* W2 = (const float*)d_in[3];
    const float* B2 = (const float*)d_in[4];
    const float* W3 = (const float*)d_in[5];
    const float* B3 = (const float*)d_in[6];
    const float* W4 = (const float*)d_in[7];
    const float* B4 = (const float*)d_in[8];
    const int nrows = in_sizes[0] / 2;

    uint2* gtab = (uint2*)d_ws;  // 64 KB
    build_table_i16<<<(TAB_QWORDS + 255) / 256, 256, 0, stream>>>(
        W1, B1, W2, B2, W3, B3, W4, B4, gtab);

    const int rows_per_block = TROWS * BLOCK;  // 4096
    const int blocks = (nrows + rows_per_block - 1) / rows_per_block;  // 512
    realnvp_i16<<<blocks, BLOCK, 0, stream>>>(x, gtab, (float*)d_out, nrows);
}